// Round 8
// baseline (164.398 us; speedup 1.0000x reference)
//
#include <hip/hip_runtime.h>

// Problem constants (setup_inputs is fixed):
//   b=4, n1=16384, n2=4096  -> N1=65536 fine points, N2=16384 coarse points
//   Cin(x1)=64, Cin(x2)=128, Cout=64
#define N1T 65536
#define N2T 16384
#define COUT 64
#define CH 192            // Cout*3 channels, point-major
#define GRD 8             // knn grid resolution per dim
#define HCELL 0.125f

// ---------------------------------------------------------------------------
// VN linear + leaky-ReLU (+ optional fused interpolation-add epilogue).
// 512 threads = 8 waves; each wave owns 8 output channels (48 accumulator
// VGPRs), lane = point. Software-pipelined main loop: ping-pong A/B groups
// of 4 input channels (12 rows) so the 12 global loads of group g+1 are in
// flight during group g's 192 FMAs (384cy >> ~200cy L2 latency). R7 showed
// the compiler won't do this on its own (VGPR=64, VALUBusy=39%).
// ---------------------------------------------------------------------------
template<int CIN, int N, bool FUSE>
__global__ __launch_bounds__(512, 4) void vn_kernel(
    const float* __restrict__ x,    // [CIN][3][N]
    const float* __restrict__ wf,   // [COUT][CIN]
    const float* __restrict__ wd,   // [COUT][CIN]
    const int*   __restrict__ idxs, // [3][N1] (FUSE only)
    const float* __restrict__ wts,  // [3][N1] (FUSE only)
    const float* __restrict__ y2t,  // [N2][192] (FUSE only)
    float* __restrict__ out)        // FUSE ? [192][N1] : [N][192] point-major
{
    const int tid  = threadIdx.x;
    const int lane = tid & 63;
    const int wave = tid >> 6;                  // 0..7
    const int n0   = blockIdx.x * 64;
    const int o0   = __builtin_amdgcn_readfirstlane(wave * 8);

    float pa[8][3], da[8][3];
#pragma unroll
    for (int oo = 0; oo < 8; ++oo)
#pragma unroll
        for (int v = 0; v < 3; ++v) { pa[oo][v] = 0.f; da[oo][v] = 0.f; }

    const float* __restrict__ xp  = x + n0 + lane;
    const float* __restrict__ wfo = wf + o0 * CIN;
    const float* __restrict__ wdo = wd + o0 * CIN;

    // one "group" = 4 input channels = 12 consecutive rows of x
    auto LOADG = [&](float (&dst)[12], int g) {
#pragma unroll
        for (int j = 0; j < 12; ++j)
            dst[j] = xp[(size_t)(g * 12 + j) * N];
    };
    auto FMAG = [&](const float (&src)[12], int g) {
#pragma unroll
        for (int oo = 0; oo < 8; ++oo) {
            const float4 wf4 = *(const float4*)&wfo[oo * CIN + g * 4];
            const float4 wd4 = *(const float4*)&wdo[oo * CIN + g * 4];
#pragma unroll
            for (int v = 0; v < 3; ++v) {
                pa[oo][v] = fmaf(wf4.x, src[0*3+v], pa[oo][v]);
                pa[oo][v] = fmaf(wf4.y, src[1*3+v], pa[oo][v]);
                pa[oo][v] = fmaf(wf4.z, src[2*3+v], pa[oo][v]);
                pa[oo][v] = fmaf(wf4.w, src[3*3+v], pa[oo][v]);
                da[oo][v] = fmaf(wd4.x, src[0*3+v], da[oo][v]);
                da[oo][v] = fmaf(wd4.y, src[1*3+v], da[oo][v]);
                da[oo][v] = fmaf(wd4.z, src[2*3+v], da[oo][v]);
                da[oo][v] = fmaf(wd4.w, src[3*3+v], da[oo][v]);
            }
        }
    };

    constexpr int NG = CIN / 4;                 // 16 (vn1) or 32 (vn2), even
    float A[12], B[12];
    LOADG(A, 0);
    int g = 0;
    for (; g + 2 < NG; g += 2) {
        LOADG(B, g + 1);
        FMAG(A, g);
        LOADG(A, g + 2);
        FMAG(B, g + 1);
    }
    LOADG(B, NG - 1);                           // g == NG-2 here
    FMAG(A, NG - 2);
    FMAG(B, NG - 1);

    float r[24];
#pragma unroll
    for (int oo = 0; oo < 8; ++oo) {
        const float p0 = pa[oo][0], p1 = pa[oo][1], p2 = pa[oo][2];
        const float q0 = da[oo][0], q1 = da[oo][1], q2 = da[oo][2];
        const float dot = p0*q0 + p1*q1 + p2*q2;
        const float dd  = q0*q0 + q1*q1 + q2*q2;
        const float coef = (dot < 0.f) ? (0.8f * dot / (dd + 1e-6f)) : 0.f;
        r[oo*3+0] = p0 - coef * q0;
        r[oo*3+1] = p1 - coef * q1;
        r[oo*3+2] = p2 - coef * q2;
    }

    if constexpr (!FUSE) {
        // point-major [n][o*3+v]; 24 contiguous floats per lane -> 6x float4
        float* op = out + (size_t)(n0 + lane) * CH + o0 * 3;
#pragma unroll
        for (int f = 0; f < 6; ++f)
            *(float4*)&op[f*4] = make_float4(r[f*4+0], r[f*4+1], r[f*4+2], r[f*4+3]);
    } else {
        __shared__ float tile[64][97];          // 64 pts x 96-ch half (+pad)
        __shared__ int   sk[3][64];
        __shared__ float sw[3][64];
        if (tid < 192) {
            const int rr = tid >> 6, pt = tid & 63;
            sk[rr][pt] = idxs[rr * N1T + n0 + pt];
            sw[rr][pt] = wts[rr * N1T + n0 + pt];
        }
#pragma unroll
        for (int h = 0; h < 2; ++h) {
            __syncthreads();                    // sk/sw ready; tile free
            if ((wave >> 2) == h) {             // waves 0-3 own ch 0-95, 4-7 own 96-191
                const int col0 = (wave & 3) * 24;
#pragma unroll
                for (int j = 0; j < 24; ++j) tile[lane][col0 + j] = r[j];
            }
            __syncthreads();
            // gather-add, ch-fast (coalesced 768B y2t rows)
#pragma unroll
            for (int k = 0; k < 12; ++k) {
                const int e  = k * 512 + tid;   // 0..6143 = pt*96 + ch
                const int pt = e / 96, ch = e - pt * 96;
                const int gch = h * 96 + ch;
                tile[pt][ch] += sw[0][pt] * y2t[(size_t)sk[0][pt] * CH + gch]
                              + sw[1][pt] * y2t[(size_t)sk[1][pt] * CH + gch]
                              + sw[2][pt] * y2t[(size_t)sk[2][pt] * CH + gch];
            }
            __syncthreads();
            // store, pt-fast (256B contiguous per wave)
#pragma unroll
            for (int k = 0; k < 12; ++k) {
                const int f  = k * 512 + tid;   // 0..6143 = ch*64 + pt
                const int ch = f >> 6, pt = f & 63;
                out[(size_t)(h * 96 + ch) * N1T + n0 + pt] = tile[pt][ch];
            }
        }
    }
}

// ---------------------------------------------------------------------------
// kNN via uniform-grid binning. Branchless full-precision top-3 insert.
// ---------------------------------------------------------------------------
#define KNN_INSERT(d2, j)                                        \
    {                                                            \
        const bool c0 = (d2) < b0;                               \
        const bool c1 = (d2) < b1;                               \
        const bool c2 = (d2) < b2v;                              \
        const float nb2 = c2 ? (c1 ? b1 : (d2)) : b2v;           \
        const int   ni2 = c2 ? (c1 ? i1 : (j))  : i2;            \
        const float nb1 = c1 ? (c0 ? b0 : (d2)) : b1;            \
        const int   ni1 = c1 ? (c0 ? i0 : (j))  : i1;            \
        b0 = c0 ? (d2) : b0;  i0 = c0 ? (j) : i0;                \
        b1 = nb1; i1 = ni1; b2v = nb2; i2 = ni2;                 \
    }

__global__ __launch_bounds__(256) void zero_kernel(int* __restrict__ p, int n) {
    const int i = blockIdx.x * 256 + threadIdx.x;
    if (i < n) p[i] = 0;
}

__device__ __forceinline__ int cell_of(float x, float y, float z) {
    int cx = (int)(x * (float)GRD); cx = cx < 0 ? 0 : (cx > GRD-1 ? GRD-1 : cx);
    int cy = (int)(y * (float)GRD); cy = cy < 0 ? 0 : (cy > GRD-1 ? GRD-1 : cy);
    int cz = (int)(z * (float)GRD); cz = cz < 0 ? 0 : (cz > GRD-1 ? GRD-1 : cz);
    return (cz << 6) | (cy << 3) | cx;
}

__global__ __launch_bounds__(256) void bin_count_kernel(
    const float* __restrict__ p2, int* __restrict__ counts) {
    const int i = blockIdx.x * 256 + threadIdx.x;      // 0..16383
    const float x = p2[i*3+0], y = p2[i*3+1], z = p2[i*3+2];
    const int cell = ((i >> 12) << 9) | cell_of(x, y, z);
    atomicAdd(&counts[cell], 1);
}

// exclusive scan of counts[2048] -> off[0..2048]
__global__ __launch_bounds__(256) void scan_kernel(
    const int* __restrict__ counts, int* __restrict__ off) {
    __shared__ int buf[2][256];
    const int t = threadIdx.x;
    int v[8]; int s = 0;
#pragma unroll
    for (int j = 0; j < 8; ++j) { const int tmp = counts[t*8+j]; v[j] = s; s += tmp; }
    buf[0][t] = s; __syncthreads();
    int src = 0;
    for (int d = 1; d < 256; d <<= 1) {
        int val = buf[src][t];
        if (t >= d) val += buf[src][t - d];
        buf[src ^ 1][t] = val; src ^= 1; __syncthreads();
    }
    const int incl = buf[src][t];
    const int base = incl - s;
#pragma unroll
    for (int j = 0; j < 8; ++j) off[t*8+j] = base + v[j];
    if (t == 255) off[2048] = incl;
}

__global__ __launch_bounds__(256) void bin_scatter_kernel(
    const float* __restrict__ p2, const int* __restrict__ off,
    int* __restrict__ cnt2, float4* __restrict__ binned) {
    const int i = blockIdx.x * 256 + threadIdx.x;      // 0..16383
    const float x = p2[i*3+0], y = p2[i*3+1], z = p2[i*3+2];
    const int cell = ((i >> 12) << 9) | cell_of(x, y, z);
    const int pos = off[cell] + atomicAdd(&cnt2[cell], 1);
    binned[pos] = make_float4(x, y, z, __int_as_float(i));
}

// 4 lanes per query; each scans a quarter of every neighbor cell's range,
// then butterfly shfl-xor merge (width 4). Exact: accept only if 3rd-best
// dist is closer than any unscanned region; else masked rescan (rare).
__global__ __launch_bounds__(256) void knn_grid_kernel(
    const float* __restrict__ p1,      // [N1][3]
    const float4* __restrict__ binned, // [N2] (x,y,z,idx)
    const int* __restrict__ off,       // [2049]
    int*   __restrict__ idx_out,       // [3][N1]
    float* __restrict__ w_out)         // [3][N1]
{
    const int t   = blockIdx.x * 256 + threadIdx.x;
    const int fp  = t >> 2;
    const int sub = t & 3;
    const int bi  = fp >> 14;
    const int cbase = bi << 9;

    const float qx = p1[fp*3+0], qy = p1[fp*3+1], qz = p1[fp*3+2];
    int cx = (int)(qx * (float)GRD); cx = cx < 0 ? 0 : (cx > 7 ? 7 : cx);
    int cy = (int)(qy * (float)GRD); cy = cy < 0 ? 0 : (cy > 7 ? 7 : cy);
    int cz = (int)(qz * (float)GRD); cz = cz < 0 ? 0 : (cz > 7 ? 7 : cz);

    float b0 = 1e30f, b1 = 1e30f, b2v = 1e30f;
    int   i0 = 0,     i1 = 0,     i2 = 0;

    for (int dz = -1; dz <= 1; ++dz)
    for (int dy = -1; dy <= 1; ++dy)
    for (int dx = -1; dx <= 1; ++dx) {
        const int nx = cx + dx, ny = cy + dy, nz = cz + dz;
        if ((unsigned)nx > 7u || (unsigned)ny > 7u || (unsigned)nz > 7u) continue;
        const int c = cbase + (nz << 6) + (ny << 3) + nx;
        const int s = off[c], e = off[c + 1];
        for (int k = s + sub; k < e; k += 4) {
            const float4 c4 = binned[k];
            const float ddx = qx - c4.x, ddy = qy - c4.y, ddz = qz - c4.z;
            const float d2 = fmaf(ddx, ddx, fmaf(ddy, ddy, ddz * ddz));
            const int j = __float_as_int(c4.w);
            KNN_INSERT(d2, j)
        }
    }

    // butterfly merge across the 4 sub-lanes
#pragma unroll
    for (int m = 1; m <= 2; m <<= 1) {
        const float c0v = __shfl_xor(b0, m, 4);
        const float c1v = __shfl_xor(b1, m, 4);
        const float c2v = __shfl_xor(b2v, m, 4);
        const int   j0v = __shfl_xor(i0, m, 4);
        const int   j1v = __shfl_xor(i1, m, 4);
        const int   j2v = __shfl_xor(i2, m, 4);
        KNN_INSERT(c0v, j0v)
        KNN_INSERT(c1v, j1v)
        KNN_INSERT(c2v, j2v)
    }

    // exactness check: nearest unscanned region (walls beyond [0,1] excluded)
    float dw = 1e30f;
    if (cx >= 2) dw = fminf(dw, qx - (float)(cx - 1) * HCELL);
    if (cx <= 5) dw = fminf(dw, (float)(cx + 2) * HCELL - qx);
    if (cy >= 2) dw = fminf(dw, qy - (float)(cy - 1) * HCELL);
    if (cy <= 5) dw = fminf(dw, (float)(cy + 2) * HCELL - qy);
    if (cz >= 2) dw = fminf(dw, qz - (float)(cz - 1) * HCELL);
    if (cz <= 5) dw = fminf(dw, (float)(cz + 2) * HCELL - qz);
    const bool done = b2v < dw * dw;

    if (!done) {   // rare; quad-uniform predicate (post-merge state identical)
        b0 = b1 = b2v = 1e30f; i0 = i1 = i2 = 0;
        const int s = bi << 12, e = (bi + 1) << 12;
        for (int k = s + sub; k < e; k += 4) {
            const float4 c4 = binned[k];
            const float ddx = qx - c4.x, ddy = qy - c4.y, ddz = qz - c4.z;
            const float d2 = fmaf(ddx, ddx, fmaf(ddy, ddy, ddz * ddz));
            const int j = __float_as_int(c4.w);
            KNN_INSERT(d2, j)
        }
#pragma unroll
        for (int m = 1; m <= 2; m <<= 1) {
            const float c0v = __shfl_xor(b0, m, 4);
            const float c1v = __shfl_xor(b1, m, 4);
            const float c2v = __shfl_xor(b2v, m, 4);
            const int   j0v = __shfl_xor(i0, m, 4);
            const int   j1v = __shfl_xor(i1, m, 4);
            const int   j2v = __shfl_xor(i2, m, 4);
            KNN_INSERT(c0v, j0v)
            KNN_INSERT(c1v, j1v)
            KNN_INSERT(c2v, j2v)
        }
    }

    if (sub == 0) {
        const float w0 = 1.f / (b0 + 1e-8f);
        const float w1 = 1.f / (b1 + 1e-8f);
        const float w2 = 1.f / (b2v + 1e-8f);
        const float inv = 1.f / (w0 + w1 + w2);
        idx_out[0*N1T + fp] = i0;
        idx_out[1*N1T + fp] = i1;
        idx_out[2*N1T + fp] = i2;
        w_out[0*N1T + fp] = w0 * inv;
        w_out[1*N1T + fp] = w1 * inv;
        w_out[2*N1T + fp] = w2 * inv;
    }
}

// ---------------------------------------------------------------------------
extern "C" void kernel_launch(void* const* d_in, const int* in_sizes, int n_in,
                              void* d_out, int out_size, void* d_ws, size_t ws_size,
                              hipStream_t stream) {
    const float* p1      = (const float*)d_in[0];
    const float* x1      = (const float*)d_in[1];
    const float* p2      = (const float*)d_in[3];
    const float* x2      = (const float*)d_in[4];
    const float* w1_feat = (const float*)d_in[6];
    const float* w1_dir  = (const float*)d_in[7];
    const float* w2_feat = (const float*)d_in[8];
    const float* w2_dir  = (const float*)d_in[9];
    float* out = (float*)d_out;

    // workspace layout (all chunks 16B-aligned)
    char* ws = (char*)d_ws;
    float*  y2t    = (float*)ws;                 ws += (size_t)N2T * CH * 4;   // 12.58 MB
    int*    idxs   = (int*)ws;                   ws += (size_t)3 * N1T * 4;    // 0.75 MB
    float*  wts    = (float*)ws;                 ws += (size_t)3 * N1T * 4;    // 0.75 MB
    int*    counts = (int*)ws;                   ws += 2048 * 4;
    int*    cnt2   = (int*)ws;                   ws += 2048 * 4;
    int*    off    = (int*)ws;                   ws += 2064 * 4;               // 2049 used
    float4* binned = (float4*)ws;                                              // 16384*16B

    // ---- kNN chain ----
    zero_kernel<<<16, 256, 0, stream>>>(counts, 4096);        // counts + cnt2 (contiguous)
    bin_count_kernel<<<N2T/256, 256, 0, stream>>>(p2, counts);
    scan_kernel<<<1, 256, 0, stream>>>(counts, off);
    bin_scatter_kernel<<<N2T/256, 256, 0, stream>>>(p2, off, cnt2, binned);
    knn_grid_kernel<<<(4*N1T)/256, 256, 0, stream>>>(p1, binned, off, idxs, wts);

    // y2 = VN(x2) -> point-major [N2][192]
    vn_kernel<128, N2T, false><<<N2T/64, 512, 0, stream>>>(
        x2, w2_feat, w2_dir, nullptr, nullptr, nullptr, y2t);
    // out = VN(x1) + interpolate(y2)   (fused epilogue)
    vn_kernel<64, N1T, true><<<N1T/64, 512, 0, stream>>>(
        x1, w1_feat, w1_dir, idxs, wts, y2t, out);
}

// Round 9
// 147.810 us; speedup vs baseline: 1.1122x; 1.1122x over previous
//
#include <hip/hip_runtime.h>

// Problem constants (setup_inputs is fixed):
//   b=4, n1=16384, n2=4096  -> N1=65536 fine points, N2=16384 coarse points
//   Cin(x1)=64, Cin(x2)=128, Cout=64
#define N1T 65536
#define N2T 16384
#define COUT 64
#define CH 192            // Cout*3 channels, point-major
#define GRD 8             // knn grid resolution per dim
#define HCELL 0.125f

// ---------------------------------------------------------------------------
// VN linear + leaky-ReLU (+ optional fused interpolation-add epilogue).
// 512 threads = 8 waves; each wave owns 8 output channels (48 accumulator
// VGPRs), lane = point. Software-pipelined main loop: ping-pong A/B groups
// of 4 input channels (12 rows). waves_per_eu(4,4) pins the allocator to a
// 128-VGPR budget: R7/R8 showed launch_bounds min-waves alone lets the
// allocator pick 64 regs (8 waves) and spill the pipeline to scratch.
// ---------------------------------------------------------------------------
template<int CIN, int N, bool FUSE>
__global__
__attribute__((amdgpu_flat_work_group_size(512, 512), amdgpu_waves_per_eu(4, 4)))
void vn_kernel(
    const float* __restrict__ x,    // [CIN][3][N]
    const float* __restrict__ wf,   // [COUT][CIN]
    const float* __restrict__ wd,   // [COUT][CIN]
    const int*   __restrict__ idxs, // [3][N1] (FUSE only)
    const float* __restrict__ wts,  // [3][N1] (FUSE only)
    const float* __restrict__ y2t,  // [N2][192] (FUSE only)
    float* __restrict__ out)        // FUSE ? [192][N1] : [N][192] point-major
{
    const int tid  = threadIdx.x;
    const int lane = tid & 63;
    const int wave = tid >> 6;                  // 0..7
    const int n0   = blockIdx.x * 64;
    const int o0   = __builtin_amdgcn_readfirstlane(wave * 8);

    float pa[8][3], da[8][3];
#pragma unroll
    for (int oo = 0; oo < 8; ++oo)
#pragma unroll
        for (int v = 0; v < 3; ++v) { pa[oo][v] = 0.f; da[oo][v] = 0.f; }

    const float* __restrict__ xp  = x + n0 + lane;
    const float* __restrict__ wfo = wf + o0 * CIN;
    const float* __restrict__ wdo = wd + o0 * CIN;

    // one "group" = 4 input channels = 12 consecutive rows of x
    auto LOADG = [&](float (&dst)[12], int g) {
#pragma unroll
        for (int j = 0; j < 12; ++j)
            dst[j] = xp[(size_t)(g * 12 + j) * N];
    };
    auto FMAG = [&](const float (&src)[12], int g) {
#pragma unroll
        for (int oo = 0; oo < 8; ++oo) {
            const float4 wf4 = *(const float4*)&wfo[oo * CIN + g * 4];
            const float4 wd4 = *(const float4*)&wdo[oo * CIN + g * 4];
#pragma unroll
            for (int v = 0; v < 3; ++v) {
                pa[oo][v] = fmaf(wf4.x, src[0*3+v], pa[oo][v]);
                pa[oo][v] = fmaf(wf4.y, src[1*3+v], pa[oo][v]);
                pa[oo][v] = fmaf(wf4.z, src[2*3+v], pa[oo][v]);
                pa[oo][v] = fmaf(wf4.w, src[3*3+v], pa[oo][v]);
                da[oo][v] = fmaf(wd4.x, src[0*3+v], da[oo][v]);
                da[oo][v] = fmaf(wd4.y, src[1*3+v], da[oo][v]);
                da[oo][v] = fmaf(wd4.z, src[2*3+v], da[oo][v]);
                da[oo][v] = fmaf(wd4.w, src[3*3+v], da[oo][v]);
            }
        }
    };

    constexpr int NG = CIN / 4;                 // 16 (vn1) or 32 (vn2), even
    float A[12], B[12];
    LOADG(A, 0);
    int g = 0;
    for (; g + 2 < NG; g += 2) {
        LOADG(B, g + 1);
        FMAG(A, g);
        LOADG(A, g + 2);
        FMAG(B, g + 1);
    }
    LOADG(B, NG - 1);                           // g == NG-2 here
    FMAG(A, NG - 2);
    FMAG(B, NG - 1);

    float r[24];
#pragma unroll
    for (int oo = 0; oo < 8; ++oo) {
        const float p0 = pa[oo][0], p1 = pa[oo][1], p2 = pa[oo][2];
        const float q0 = da[oo][0], q1 = da[oo][1], q2 = da[oo][2];
        const float dot = p0*q0 + p1*q1 + p2*q2;
        const float dd  = q0*q0 + q1*q1 + q2*q2;
        const float coef = (dot < 0.f) ? (0.8f * dot / (dd + 1e-6f)) : 0.f;
        r[oo*3+0] = p0 - coef * q0;
        r[oo*3+1] = p1 - coef * q1;
        r[oo*3+2] = p2 - coef * q2;
    }

    if constexpr (!FUSE) {
        // point-major [n][o*3+v]; 24 contiguous floats per lane -> 6x float4
        float* op = out + (size_t)(n0 + lane) * CH + o0 * 3;
#pragma unroll
        for (int f = 0; f < 6; ++f)
            *(float4*)&op[f*4] = make_float4(r[f*4+0], r[f*4+1], r[f*4+2], r[f*4+3]);
    } else {
        __shared__ float tile[64][97];          // 64 pts x 96-ch half (+pad)
        __shared__ int   sk[3][64];
        __shared__ float sw[3][64];
        if (tid < 192) {
            const int rr = tid >> 6, pt = tid & 63;
            sk[rr][pt] = idxs[rr * N1T + n0 + pt];
            sw[rr][pt] = wts[rr * N1T + n0 + pt];
        }
#pragma unroll
        for (int h = 0; h < 2; ++h) {
            __syncthreads();                    // sk/sw ready; tile free
            if ((wave >> 2) == h) {             // waves 0-3 own ch 0-95, 4-7 own 96-191
                const int col0 = (wave & 3) * 24;
#pragma unroll
                for (int j = 0; j < 24; ++j) tile[lane][col0 + j] = r[j];
            }
            __syncthreads();
            // gather-add, ch-fast (coalesced 768B y2t rows)
#pragma unroll
            for (int k = 0; k < 12; ++k) {
                const int e  = k * 512 + tid;   // 0..6143 = pt*96 + ch
                const int pt = e / 96, ch = e - pt * 96;
                const int gch = h * 96 + ch;
                tile[pt][ch] += sw[0][pt] * y2t[(size_t)sk[0][pt] * CH + gch]
                              + sw[1][pt] * y2t[(size_t)sk[1][pt] * CH + gch]
                              + sw[2][pt] * y2t[(size_t)sk[2][pt] * CH + gch];
            }
            __syncthreads();
            // store, pt-fast (256B contiguous per wave)
#pragma unroll
            for (int k = 0; k < 12; ++k) {
                const int f  = k * 512 + tid;   // 0..6143 = ch*64 + pt
                const int ch = f >> 6, pt = f & 63;
                out[(size_t)(h * 96 + ch) * N1T + n0 + pt] = tile[pt][ch];
            }
        }
    }
}

// ---------------------------------------------------------------------------
// kNN via uniform-grid binning. Branchless full-precision top-3 insert.
// ---------------------------------------------------------------------------
#define KNN_INSERT(d2, j)                                        \
    {                                                            \
        const bool c0 = (d2) < b0;                               \
        const bool c1 = (d2) < b1;                               \
        const bool c2 = (d2) < b2v;                              \
        const float nb2 = c2 ? (c1 ? b1 : (d2)) : b2v;           \
        const int   ni2 = c2 ? (c1 ? i1 : (j))  : i2;            \
        const float nb1 = c1 ? (c0 ? b0 : (d2)) : b1;            \
        const int   ni1 = c1 ? (c0 ? i0 : (j))  : i1;            \
        b0 = c0 ? (d2) : b0;  i0 = c0 ? (j) : i0;                \
        b1 = nb1; i1 = ni1; b2v = nb2; i2 = ni2;                 \
    }

__global__ __launch_bounds__(256) void zero_kernel(int* __restrict__ p, int n) {
    const int i = blockIdx.x * 256 + threadIdx.x;
    if (i < n) p[i] = 0;
}

__device__ __forceinline__ int cell_of(float x, float y, float z) {
    int cx = (int)(x * (float)GRD); cx = cx < 0 ? 0 : (cx > GRD-1 ? GRD-1 : cx);
    int cy = (int)(y * (float)GRD); cy = cy < 0 ? 0 : (cy > GRD-1 ? GRD-1 : cy);
    int cz = (int)(z * (float)GRD); cz = cz < 0 ? 0 : (cz > GRD-1 ? GRD-1 : cz);
    return (cz << 6) | (cy << 3) | cx;
}

__global__ __launch_bounds__(256) void bin_count_kernel(
    const float* __restrict__ p2, int* __restrict__ counts) {
    const int i = blockIdx.x * 256 + threadIdx.x;      // 0..16383
    const float x = p2[i*3+0], y = p2[i*3+1], z = p2[i*3+2];
    const int cell = ((i >> 12) << 9) | cell_of(x, y, z);
    atomicAdd(&counts[cell], 1);
}

// exclusive scan of counts[2048] -> off[0..2048]
__global__ __launch_bounds__(256) void scan_kernel(
    const int* __restrict__ counts, int* __restrict__ off) {
    __shared__ int buf[2][256];
    const int t = threadIdx.x;
    int v[8]; int s = 0;
#pragma unroll
    for (int j = 0; j < 8; ++j) { const int tmp = counts[t*8+j]; v[j] = s; s += tmp; }
    buf[0][t] = s; __syncthreads();
    int src = 0;
    for (int d = 1; d < 256; d <<= 1) {
        int val = buf[src][t];
        if (t >= d) val += buf[src][t - d];
        buf[src ^ 1][t] = val; src ^= 1; __syncthreads();
    }
    const int incl = buf[src][t];
    const int base = incl - s;
#pragma unroll
    for (int j = 0; j < 8; ++j) off[t*8+j] = base + v[j];
    if (t == 255) off[2048] = incl;
}

__global__ __launch_bounds__(256) void bin_scatter_kernel(
    const float* __restrict__ p2, const int* __restrict__ off,
    int* __restrict__ cnt2, float4* __restrict__ binned) {
    const int i = blockIdx.x * 256 + threadIdx.x;      // 0..16383
    const float x = p2[i*3+0], y = p2[i*3+1], z = p2[i*3+2];
    const int cell = ((i >> 12) << 9) | cell_of(x, y, z);
    const int pos = off[cell] + atomicAdd(&cnt2[cell], 1);
    binned[pos] = make_float4(x, y, z, __int_as_float(i));
}

// 4 lanes per query; each scans a quarter of every neighbor cell's range,
// then butterfly shfl-xor merge (width 4). Exact: accept only if 3rd-best
// dist is closer than any unscanned region; else masked rescan (rare).
__global__ __launch_bounds__(256) void knn_grid_kernel(
    const float* __restrict__ p1,      // [N1][3]
    const float4* __restrict__ binned, // [N2] (x,y,z,idx)
    const int* __restrict__ off,       // [2049]
    int*   __restrict__ idx_out,       // [3][N1]
    float* __restrict__ w_out)         // [3][N1]
{
    const int t   = blockIdx.x * 256 + threadIdx.x;
    const int fp  = t >> 2;
    const int sub = t & 3;
    const int bi  = fp >> 14;
    const int cbase = bi << 9;

    const float qx = p1[fp*3+0], qy = p1[fp*3+1], qz = p1[fp*3+2];
    int cx = (int)(qx * (float)GRD); cx = cx < 0 ? 0 : (cx > 7 ? 7 : cx);
    int cy = (int)(qy * (float)GRD); cy = cy < 0 ? 0 : (cy > 7 ? 7 : cy);
    int cz = (int)(qz * (float)GRD); cz = cz < 0 ? 0 : (cz > 7 ? 7 : cz);

    float b0 = 1e30f, b1 = 1e30f, b2v = 1e30f;
    int   i0 = 0,     i1 = 0,     i2 = 0;

    for (int dz = -1; dz <= 1; ++dz)
    for (int dy = -1; dy <= 1; ++dy)
    for (int dx = -1; dx <= 1; ++dx) {
        const int nx = cx + dx, ny = cy + dy, nz = cz + dz;
        if ((unsigned)nx > 7u || (unsigned)ny > 7u || (unsigned)nz > 7u) continue;
        const int c = cbase + (nz << 6) + (ny << 3) + nx;
        const int s = off[c], e = off[c + 1];
        for (int k = s + sub; k < e; k += 4) {
            const float4 c4 = binned[k];
            const float ddx = qx - c4.x, ddy = qy - c4.y, ddz = qz - c4.z;
            const float d2 = fmaf(ddx, ddx, fmaf(ddy, ddy, ddz * ddz));
            const int j = __float_as_int(c4.w);
            KNN_INSERT(d2, j)
        }
    }

    // butterfly merge across the 4 sub-lanes
#pragma unroll
    for (int m = 1; m <= 2; m <<= 1) {
        const float c0v = __shfl_xor(b0, m, 4);
        const float c1v = __shfl_xor(b1, m, 4);
        const float c2v = __shfl_xor(b2v, m, 4);
        const int   j0v = __shfl_xor(i0, m, 4);
        const int   j1v = __shfl_xor(i1, m, 4);
        const int   j2v = __shfl_xor(i2, m, 4);
        KNN_INSERT(c0v, j0v)
        KNN_INSERT(c1v, j1v)
        KNN_INSERT(c2v, j2v)
    }

    // exactness check: nearest unscanned region (walls beyond [0,1] excluded)
    float dw = 1e30f;
    if (cx >= 2) dw = fminf(dw, qx - (float)(cx - 1) * HCELL);
    if (cx <= 5) dw = fminf(dw, (float)(cx + 2) * HCELL - qx);
    if (cy >= 2) dw = fminf(dw, qy - (float)(cy - 1) * HCELL);
    if (cy <= 5) dw = fminf(dw, (float)(cy + 2) * HCELL - qy);
    if (cz >= 2) dw = fminf(dw, qz - (float)(cz - 1) * HCELL);
    if (cz <= 5) dw = fminf(dw, (float)(cz + 2) * HCELL - qz);
    const bool done = b2v < dw * dw;

    if (!done) {   // rare; quad-uniform predicate (post-merge state identical)
        b0 = b1 = b2v = 1e30f; i0 = i1 = i2 = 0;
        const int s = bi << 12, e = (bi + 1) << 12;
        for (int k = s + sub; k < e; k += 4) {
            const float4 c4 = binned[k];
            const float ddx = qx - c4.x, ddy = qy - c4.y, ddz = qz - c4.z;
            const float d2 = fmaf(ddx, ddx, fmaf(ddy, ddy, ddz * ddz));
            const int j = __float_as_int(c4.w);
            KNN_INSERT(d2, j)
        }
#pragma unroll
        for (int m = 1; m <= 2; m <<= 1) {
            const float c0v = __shfl_xor(b0, m, 4);
            const float c1v = __shfl_xor(b1, m, 4);
            const float c2v = __shfl_xor(b2v, m, 4);
            const int   j0v = __shfl_xor(i0, m, 4);
            const int   j1v = __shfl_xor(i1, m, 4);
            const int   j2v = __shfl_xor(i2, m, 4);
            KNN_INSERT(c0v, j0v)
            KNN_INSERT(c1v, j1v)
            KNN_INSERT(c2v, j2v)
        }
    }

    if (sub == 0) {
        const float w0 = 1.f / (b0 + 1e-8f);
        const float w1 = 1.f / (b1 + 1e-8f);
        const float w2 = 1.f / (b2v + 1e-8f);
        const float inv = 1.f / (w0 + w1 + w2);
        idx_out[0*N1T + fp] = i0;
        idx_out[1*N1T + fp] = i1;
        idx_out[2*N1T + fp] = i2;
        w_out[0*N1T + fp] = w0 * inv;
        w_out[1*N1T + fp] = w1 * inv;
        w_out[2*N1T + fp] = w2 * inv;
    }
}

// ---------------------------------------------------------------------------
extern "C" void kernel_launch(void* const* d_in, const int* in_sizes, int n_in,
                              void* d_out, int out_size, void* d_ws, size_t ws_size,
                              hipStream_t stream) {
    const float* p1      = (const float*)d_in[0];
    const float* x1      = (const float*)d_in[1];
    const float* p2      = (const float*)d_in[3];
    const float* x2      = (const float*)d_in[4];
    const float* w1_feat = (const float*)d_in[6];
    const float* w1_dir  = (const float*)d_in[7];
    const float* w2_feat = (const float*)d_in[8];
    const float* w2_dir  = (const float*)d_in[9];
    float* out = (float*)d_out;

    // workspace layout (all chunks 16B-aligned)
    char* ws = (char*)d_ws;
    float*  y2t    = (float*)ws;                 ws += (size_t)N2T * CH * 4;   // 12.58 MB
    int*    idxs   = (int*)ws;                   ws += (size_t)3 * N1T * 4;    // 0.75 MB
    float*  wts    = (float*)ws;                 ws += (size_t)3 * N1T * 4;    // 0.75 MB
    int*    counts = (int*)ws;                   ws += 2048 * 4;
    int*    cnt2   = (int*)ws;                   ws += 2048 * 4;
    int*    off    = (int*)ws;                   ws += 2064 * 4;               // 2049 used
    float4* binned = (float4*)ws;                                              // 16384*16B

    // ---- kNN chain ----
    zero_kernel<<<16, 256, 0, stream>>>(counts, 4096);        // counts + cnt2 (contiguous)
    bin_count_kernel<<<N2T/256, 256, 0, stream>>>(p2, counts);
    scan_kernel<<<1, 256, 0, stream>>>(counts, off);
    bin_scatter_kernel<<<N2T/256, 256, 0, stream>>>(p2, off, cnt2, binned);
    knn_grid_kernel<<<(4*N1T)/256, 256, 0, stream>>>(p1, binned, off, idxs, wts);

    // y2 = VN(x2) -> point-major [N2][192]
    vn_kernel<128, N2T, false><<<N2T/64, 512, 0, stream>>>(
        x2, w2_feat, w2_dir, nullptr, nullptr, nullptr, y2t);
    // out = VN(x1) + interpolate(y2)   (fused epilogue)
    vn_kernel<64, N1T, true><<<N1T/64, 512, 0, stream>>>(
        x1, w1_feat, w1_dir, idxs, wts, y2t, out);
}